// Round 2
// baseline (2105.156 us; speedup 1.0000x reference)
//
#include <hip/hip_runtime.h>

// SGC: h = relu(x @ W^T + b); 3x { h = segment_sum(h[src]*w, dst) }
// Sizes fixed by setup_inputs().
constexpr int N_NODES_C = 100000;
constexpr int N_EDGES_C = 1600000;
constexpr int IN_DIM_C  = 128;
constexpr int EMB       = 32;

// ---------------------------------------------------------------------------
// Kernel 1: h0[n][e] = relu(sum_k x[n][k]*W[e][k] + b[e])
// One thread per row; W/b accessed with wave-uniform addresses -> scalar loads
// through the constant cache (W is only 16 KB, fully K$-resident).
// ---------------------------------------------------------------------------
__global__ __launch_bounds__(256) void linear_relu_kernel(
    const float* __restrict__ x, const float* __restrict__ W,
    const float* __restrict__ b, float* __restrict__ h, int n)
{
    int row = blockIdx.x * 256 + threadIdx.x;
    if (row >= n) return;
    const float4* __restrict__ xr =
        reinterpret_cast<const float4*>(x + (size_t)row * IN_DIM_C);
    const float4* __restrict__ W4 = reinterpret_cast<const float4*>(W);

    float acc[EMB];
#pragma unroll
    for (int e = 0; e < EMB; ++e) acc[e] = 0.f;

#pragma unroll 2
    for (int k4 = 0; k4 < IN_DIM_C / 4; ++k4) {
        float4 xv = xr[k4];
#pragma unroll
        for (int e = 0; e < EMB; ++e) {
            float4 wv = W4[e * (IN_DIM_C / 4) + k4];  // wave-uniform -> s_load
            acc[e] = fmaf(xv.x, wv.x,
                     fmaf(xv.y, wv.y,
                     fmaf(xv.z, wv.z,
                     fmaf(xv.w, wv.w, acc[e]))));
        }
    }

    float* __restrict__ out = h + (size_t)row * EMB;
#pragma unroll
    for (int e = 0; e < EMB; ++e) {
        float v = acc[e] + b[e];
        out[e] = v > 0.f ? v : 0.f;
    }
}

// ---------------------------------------------------------------------------
// Kernel 2: one hop: h_out[dst] += h_in[src] * w  (h_out pre-zeroed)
// 8 lanes per edge, one float4 of the 32-dim embedding per lane.
// Gather is 128B-contiguous per edge; scatter is 4 f32 HW atomics per lane.
// unsafeAtomicAdd forces global_atomic_add_f32 (no CAS loop) on gfx950.
// ---------------------------------------------------------------------------
__global__ __launch_bounds__(256) void hop_kernel(
    const float* __restrict__ h_in, const int* __restrict__ src,
    const int* __restrict__ dst, const float* __restrict__ w,
    float* __restrict__ h_out)
{
    int tid = blockIdx.x * 256 + threadIdx.x;
    int e = tid >> 3;
    int q = tid & 7;
    if (e >= N_EDGES_C) return;

    int   s  = src[e];
    int   t  = dst[e];
    float wt = w[e];

    float4 hv = reinterpret_cast<const float4*>(h_in + (size_t)s * EMB)[q];
    float* outp = h_out + (size_t)t * EMB + q * 4;
    unsafeAtomicAdd(outp + 0, hv.x * wt);
    unsafeAtomicAdd(outp + 1, hv.y * wt);
    unsafeAtomicAdd(outp + 2, hv.z * wt);
    unsafeAtomicAdd(outp + 3, hv.w * wt);
}

extern "C" void kernel_launch(void* const* d_in, const int* in_sizes, int n_in,
                              void* d_out, int out_size, void* d_ws, size_t ws_size,
                              hipStream_t stream) {
    const float* x   = (const float*)d_in[0];
    const float* W   = (const float*)d_in[1];
    const float* b   = (const float*)d_in[2];
    const float* w   = (const float*)d_in[3];
    const int*   src = (const int*)d_in[4];
    const int*   dst = (const int*)d_in[5];
    // d_in[6] is k (== 3, fixed by setup); hardcoded below.

    float* out = (float*)d_out;
    float* h0  = (float*)d_ws;   // 12.8 MB scratch buffer

    const size_t hbytes = (size_t)N_NODES_C * EMB * sizeof(float);

    // 1) h0 = relu(x W^T + b)
    linear_relu_kernel<<<(N_NODES_C + 255) / 256, 256, 0, stream>>>(
        x, W, b, h0, N_NODES_C);

    const int hop_blocks = (N_EDGES_C * 8 + 255) / 256;  // 50000

    // 2) hop 1: h0 -> d_out
    hipMemsetAsync(d_out, 0, hbytes, stream);
    hop_kernel<<<hop_blocks, 256, 0, stream>>>(h0, src, dst, w, out);

    // 3) hop 2: d_out -> h0
    hipMemsetAsync(h0, 0, hbytes, stream);
    hop_kernel<<<hop_blocks, 256, 0, stream>>>(out, src, dst, w, h0);

    // 4) hop 3: h0 -> d_out
    hipMemsetAsync(d_out, 0, hbytes, stream);
    hop_kernel<<<hop_blocks, 256, 0, stream>>>(h0, src, dst, w, out);
}

// Round 4
// 426.910 us; speedup vs baseline: 4.9311x; 4.9311x over previous
//
#include <hip/hip_runtime.h>

// SGC: h = relu(x @ W^T + b); 3x { h = segment_sum(h[src]*w, dst) }
// Round 4 == round 3 (never ran: broker timeout) + unroll-4 on the hop gather
// loop for MLP. Round-2 profile: f32 atomicAdd scatter = 819 MB HBM
// writes/hop, 646 us/hop -> replaced by pull-based CSR hops (no f32 atomics).
constexpr int N_NODES_C = 100000;
constexpr int N_EDGES_C = 1600000;
constexpr int IN_DIM_C  = 128;
constexpr int EMB       = 32;

constexpr int SCAN_CHUNK  = 1024;                                   // elems per scan block
constexpr int SCAN_BLOCKS = (N_NODES_C + SCAN_CHUNK - 1) / SCAN_CHUNK;  // 98

// ---------------------------------------------------------------------------
// Kernel 1: h0 = relu(x W^T + b). One thread per row, W via wave-uniform
// scalar loads (16 KB, K$-resident).
// ---------------------------------------------------------------------------
__global__ __launch_bounds__(256) void linear_relu_kernel(
    const float* __restrict__ x, const float* __restrict__ W,
    const float* __restrict__ b, float* __restrict__ h, int n)
{
    int row = blockIdx.x * 256 + threadIdx.x;
    if (row >= n) return;
    const float4* __restrict__ xr =
        reinterpret_cast<const float4*>(x + (size_t)row * IN_DIM_C);
    const float4* __restrict__ W4 = reinterpret_cast<const float4*>(W);

    float acc[EMB];
#pragma unroll
    for (int e = 0; e < EMB; ++e) acc[e] = 0.f;

#pragma unroll 2
    for (int k4 = 0; k4 < IN_DIM_C / 4; ++k4) {
        float4 xv = xr[k4];
#pragma unroll
        for (int e = 0; e < EMB; ++e) {
            float4 wv = W4[e * (IN_DIM_C / 4) + k4];
            acc[e] = fmaf(xv.x, wv.x,
                     fmaf(xv.y, wv.y,
                     fmaf(xv.z, wv.z,
                     fmaf(xv.w, wv.w, acc[e]))));
        }
    }

    float* __restrict__ out = h + (size_t)row * EMB;
#pragma unroll
    for (int e = 0; e < EMB; ++e) {
        float v = acc[e] + b[e];
        out[e] = v > 0.f ? v : 0.f;
    }
}

// ---------------------------------------------------------------------------
// CSR build: histogram -> 3-phase exclusive scan -> permute {src,w} by dst.
// ---------------------------------------------------------------------------
__global__ __launch_bounds__(256) void hist_kernel(
    const int* __restrict__ dst, int* __restrict__ deg)
{
    int e = blockIdx.x * 256 + threadIdx.x;
    if (e < N_EDGES_C) atomicAdd(&deg[dst[e]], 1);
}

// Phase A: per-block (1024-elem chunk) sum of deg -> partial[b]
__global__ __launch_bounds__(256) void scan_phase_a(
    const int* __restrict__ deg, int* __restrict__ partial)
{
    int b = blockIdx.x, t = threadIdx.x;
    int base = b * SCAN_CHUNK + t * 4;
    int s = 0;
#pragma unroll
    for (int i = 0; i < 4; ++i)
        s += (base + i < N_NODES_C) ? deg[base + i] : 0;
    // wave reduce (64 lanes)
#pragma unroll
    for (int ofs = 32; ofs >= 1; ofs >>= 1) s += __shfl_down(s, ofs, 64);
    __shared__ int wsum[4];
    int lane = t & 63, wid = t >> 6;
    if (lane == 0) wsum[wid] = s;
    __syncthreads();
    if (t == 0) partial[b] = wsum[0] + wsum[1] + wsum[2] + wsum[3];
}

// Phase B: serial exclusive scan of the 98 partials; also writes off[N]=E.
__global__ void scan_phase_b(const int* __restrict__ partial,
                             int* __restrict__ block_base,
                             int* __restrict__ off)
{
    if (threadIdx.x == 0) {
        int run = 0;
        for (int i = 0; i < SCAN_BLOCKS; ++i) { block_base[i] = run; run += partial[i]; }
        off[N_NODES_C] = run;  // == N_EDGES_C
    }
}

// Phase C: per-chunk exclusive scan + block base -> off[]
__global__ __launch_bounds__(256) void scan_phase_c(
    const int* __restrict__ deg, const int* __restrict__ block_base,
    int* __restrict__ off)
{
    int b = blockIdx.x, t = threadIdx.x;
    int base = b * SCAN_CHUNK + t * 4;
    int d[4];
#pragma unroll
    for (int i = 0; i < 4; ++i)
        d[i] = (base + i < N_NODES_C) ? deg[base + i] : 0;
    int tsum = d[0] + d[1] + d[2] + d[3];

    int lane = t & 63, wid = t >> 6;
    int v = tsum;
#pragma unroll
    for (int ofs = 1; ofs < 64; ofs <<= 1) {
        int u = __shfl_up(v, ofs, 64);
        if (lane >= ofs) v += u;
    }
    __shared__ int wsum[4];
    if (lane == 63) wsum[wid] = v;
    __syncthreads();
    int wofs = 0;
    for (int i = 0; i < wid; ++i) wofs += wsum[i];

    int gbase = block_base[b] + wofs + (v - tsum);  // exclusive prefix
#pragma unroll
    for (int i = 0; i < 4; ++i) {
        if (base + i < N_NODES_C) off[base + i] = gbase;
        gbase += d[i];
    }
}

// Fill: scatter {src, w} into dst-ordered slots. cur[] pre-zeroed.
__global__ __launch_bounds__(256) void fill_kernel(
    const int* __restrict__ src, const int* __restrict__ dst,
    const float* __restrict__ w, const int* __restrict__ off,
    int* __restrict__ cur, int2* __restrict__ edge_pack)
{
    int e = blockIdx.x * 256 + threadIdx.x;
    if (e >= N_EDGES_C) return;
    int d = dst[e];
    int pos = off[d] + atomicAdd(&cur[d], 1);
    edge_pack[pos] = make_int2(src[e], __float_as_int(w[e]));
}

// ---------------------------------------------------------------------------
// Hop (pull): 8 lanes per node, one float4 of the embedding per lane.
// No atomics; each node row written exactly once. Unroll-4 for gather MLP.
// ---------------------------------------------------------------------------
__global__ __launch_bounds__(256) void hop_csr_kernel(
    const float* __restrict__ h_in, const int* __restrict__ off,
    const int2* __restrict__ edge_pack, float* __restrict__ h_out)
{
    int tid = blockIdx.x * 256 + threadIdx.x;
    int node = tid >> 3;
    int q    = tid & 7;
    if (node >= N_NODES_C) return;

    int beg = off[node], end = off[node + 1];
    float4 acc = make_float4(0.f, 0.f, 0.f, 0.f);
    int j = beg;
    // main unrolled-by-4 body: 4 independent gathers in flight
    for (; j + 4 <= end; j += 4) {
        int2 ep0 = edge_pack[j + 0];
        int2 ep1 = edge_pack[j + 1];
        int2 ep2 = edge_pack[j + 2];
        int2 ep3 = edge_pack[j + 3];
        float4 h0 = *reinterpret_cast<const float4*>(h_in + (size_t)ep0.x * EMB + q * 4);
        float4 h1 = *reinterpret_cast<const float4*>(h_in + (size_t)ep1.x * EMB + q * 4);
        float4 h2 = *reinterpret_cast<const float4*>(h_in + (size_t)ep2.x * EMB + q * 4);
        float4 h3 = *reinterpret_cast<const float4*>(h_in + (size_t)ep3.x * EMB + q * 4);
        float w0 = __int_as_float(ep0.y), w1 = __int_as_float(ep1.y);
        float w2 = __int_as_float(ep2.y), w3 = __int_as_float(ep3.y);
        acc.x = fmaf(h0.x, w0, acc.x); acc.y = fmaf(h0.y, w0, acc.y);
        acc.z = fmaf(h0.z, w0, acc.z); acc.w = fmaf(h0.w, w0, acc.w);
        acc.x = fmaf(h1.x, w1, acc.x); acc.y = fmaf(h1.y, w1, acc.y);
        acc.z = fmaf(h1.z, w1, acc.z); acc.w = fmaf(h1.w, w1, acc.w);
        acc.x = fmaf(h2.x, w2, acc.x); acc.y = fmaf(h2.y, w2, acc.y);
        acc.z = fmaf(h2.z, w2, acc.z); acc.w = fmaf(h2.w, w2, acc.w);
        acc.x = fmaf(h3.x, w3, acc.x); acc.y = fmaf(h3.y, w3, acc.y);
        acc.z = fmaf(h3.z, w3, acc.z); acc.w = fmaf(h3.w, w3, acc.w);
    }
    for (; j < end; ++j) {
        int2  ep = edge_pack[j];
        float wt = __int_as_float(ep.y);
        float4 hv = *reinterpret_cast<const float4*>(
            h_in + (size_t)ep.x * EMB + q * 4);
        acc.x = fmaf(hv.x, wt, acc.x);
        acc.y = fmaf(hv.y, wt, acc.y);
        acc.z = fmaf(hv.z, wt, acc.z);
        acc.w = fmaf(hv.w, wt, acc.w);
    }
    *reinterpret_cast<float4*>(h_out + (size_t)node * EMB + q * 4) = acc;
}

extern "C" void kernel_launch(void* const* d_in, const int* in_sizes, int n_in,
                              void* d_out, int out_size, void* d_ws, size_t ws_size,
                              hipStream_t stream) {
    const float* x   = (const float*)d_in[0];
    const float* W   = (const float*)d_in[1];
    const float* b   = (const float*)d_in[2];
    const float* w   = (const float*)d_in[3];
    const int*   src = (const int*)d_in[4];
    const int*   dst = (const int*)d_in[5];
    // d_in[6] is k (== 3, fixed by setup); hardcoded.

    float* out = (float*)d_out;

    // Workspace layout (all 256B-aligned):
    char* ws = (char*)d_ws;
    size_t o = 0;
    auto alloc = [&](size_t bytes) {
        char* p = ws + o;
        o += (bytes + 255) & ~(size_t)255;
        return p;
    };
    float* h0        = (float*)alloc((size_t)N_NODES_C * EMB * sizeof(float));  // 12.8 MB
    int*   deg       = (int*)  alloc((size_t)N_NODES_C * sizeof(int));          // 400 KB
    int*   off       = (int*)  alloc((size_t)(N_NODES_C + 1) * sizeof(int));    // 400 KB
    int*   cur       = (int*)  alloc((size_t)N_NODES_C * sizeof(int));          // 400 KB
    int*   partial   = (int*)  alloc((size_t)SCAN_BLOCKS * sizeof(int));
    int*   blockbase = (int*)  alloc((size_t)SCAN_BLOCKS * sizeof(int));
    int2*  edge_pack = (int2*) alloc((size_t)N_EDGES_C * sizeof(int2));         // 12.8 MB

    const int EB = (N_EDGES_C + 255) / 256;     // 6250 blocks over edges
    const int HB = (N_NODES_C * 8 + 255) / 256; // 3125 blocks over node-octets

    // --- CSR build ---
    hipMemsetAsync(deg, 0, (size_t)N_NODES_C * sizeof(int), stream);
    hist_kernel<<<EB, 256, 0, stream>>>(dst, deg);
    scan_phase_a<<<SCAN_BLOCKS, 256, 0, stream>>>(deg, partial);
    scan_phase_b<<<1, 64, 0, stream>>>(partial, blockbase, off);
    scan_phase_c<<<SCAN_BLOCKS, 256, 0, stream>>>(deg, blockbase, off);
    hipMemsetAsync(cur, 0, (size_t)N_NODES_C * sizeof(int), stream);
    fill_kernel<<<EB, 256, 0, stream>>>(src, dst, w, off, cur, edge_pack);

    // --- h0 = relu(x W^T + b) ---
    linear_relu_kernel<<<(N_NODES_C + 255) / 256, 256, 0, stream>>>(
        x, W, b, h0, N_NODES_C);

    // --- 3 pull-hops: h0 -> out -> h0 -> out ---
    hop_csr_kernel<<<HB, 256, 0, stream>>>(h0, off, edge_pack, out);
    hop_csr_kernel<<<HB, 256, 0, stream>>>(out, off, edge_pack, h0);
    hop_csr_kernel<<<HB, 256, 0, stream>>>(h0, off, edge_pack, out);
}